// Round 8
// baseline (221.809 us; speedup 1.0000x reference)
//
#include <hip/hip_runtime.h>
#include <math.h>

#define K_INST 256
#define ATTRACTION_W 1.0f
#define REPULSION_W 1.0f
#define BETA_POS_W 1.0f
#define BETA_NEG_W 0.5f

typedef float f32x4 __attribute__((ext_vector_type(4)));
typedef int i32x4 __attribute__((ext_vector_type(4)));

__device__ inline float softplusf(float x) {
    return fmaxf(x, 0.f) + log1pf(expf(-fabsf(x)));
}

__device__ inline float waveReduceSumF(float v) {
    for (int o = 32; o; o >>= 1) v += __shfl_xor(v, o);
    return v;
}
__device__ inline int waveReduceSumI(int v) {
    for (int o = 32; o; o >>= 1) v += __shfl_xor(v, o);
    return v;
}

// 4 points per thread + sid histogram. grid (N/1024, B), block 256.
__global__ void stats_kernel(const float* __restrict__ beta,
                             const int* __restrict__ sid,
                             const int* __restrict__ is_cp,
                             int* first_cp,
                             float* pos_sum, float* neg_sum,
                             int* seg_cnt,
                             int* cpv_cnt, int* noncp_cnt, int* valid_cnt,
                             int N) {
    int b = blockIdx.y;
    int base = (blockIdx.x * blockDim.x + threadIdx.x) * 4;
    const float* betaB = beta + (size_t)b * N;
    const int* sidB = sid + (size_t)b * N;
    const int* cpB = is_cp + (size_t)b * N;

    __shared__ int hist[K_INST];
    for (int k = threadIdx.x; k < K_INST; k += blockDim.x) hist[k] = 0;
    __syncthreads();

    i32x4 s4 = *(const i32x4*)(sidB + base);
    i32x4 c4 = *(const i32x4*)(cpB + base);
    f32x4 x4 = *(const f32x4*)(betaB + base);

    float pos = 0.f, neg = 0.f;
    int c_cpv = 0, c_non = 0, c_val = 0;
    #pragma unroll
    for (int e = 0; e < 4; ++e) {
        int s = s4[e], cp = c4[e];
        float x = x4[e];
        bool valid = s >= 0;
        bool cpv = cp && valid;
        if (valid) atomicAdd(&hist[s], 1);
        if (cpv) {
            pos += softplusf(-x);
            c_cpv++;
            atomicMin(&first_cp[b * K_INST + s], base + e);
        }
        if (!cp) {
            neg += softplusf(x);
            c_non++;
        }
        c_val += valid ? 1 : 0;
    }

    __shared__ float sf[2][4];
    __shared__ int si[3][4];
    pos = waveReduceSumF(pos);
    neg = waveReduceSumF(neg);
    c_cpv = waveReduceSumI(c_cpv);
    c_non = waveReduceSumI(c_non);
    c_val = waveReduceSumI(c_val);
    int wave = threadIdx.x >> 6, lane = threadIdx.x & 63;
    if (lane == 0) {
        sf[0][wave] = pos; sf[1][wave] = neg;
        si[0][wave] = c_cpv; si[1][wave] = c_non; si[2][wave] = c_val;
    }
    __syncthreads();
    if (threadIdx.x == 0) {
        float p = sf[0][0] + sf[0][1] + sf[0][2] + sf[0][3];
        float n = sf[1][0] + sf[1][1] + sf[1][2] + sf[1][3];
        int a = si[0][0] + si[0][1] + si[0][2] + si[0][3];
        int c = si[1][0] + si[1][1] + si[1][2] + si[1][3];
        int v = si[2][0] + si[2][1] + si[2][2] + si[2][3];
        if (p != 0.f) atomicAdd(&pos_sum[b], p);
        if (n != 0.f) atomicAdd(&neg_sum[b], n);
        if (a) atomicAdd(&cpv_cnt[b], a);
        if (c) atomicAdd(&noncp_cnt[b], c);
        if (v) atomicAdd(&valid_cnt[b], v);
    }
    // flush histogram
    for (int k = threadIdx.x; k < K_INST; k += blockDim.x) {
        int h = hist[k];
        if (h) atomicAdd(&seg_cnt[b * K_INST + k], h);
    }
}

// one block per (k, b), 64 threads. writes row + transposed scatter.
__global__ void gather_kernel(const float* __restrict__ embed,
                              const int* __restrict__ first_cp,
                              float* __restrict__ cp_emb,
                              float* __restrict__ cp_embT, int N) {
    int b = blockIdx.y;
    int k = blockIdx.x;
    int src = first_cp[b * K_INST + k];
    if (src >= N) src = N - 1;
    int lane = threadIdx.x;
    const float* embB = embed + (size_t)b * N * 256;
    f32x4 v = ((const f32x4*)(embB + (size_t)src * 256))[lane];
    ((f32x4*)(cp_emb + ((size_t)b * K_INST + k) * 256))[lane] = v;
    float* T = cp_embT + (size_t)b * K_INST * 256;
    int d = lane * 4;
    T[(size_t)(d + 0) * 256 + k] = v[0];
    T[(size_t)(d + 1) * 256 + k] = v[1];
    T[(size_t)(d + 2) * 256 + k] = v[2];
    T[(size_t)(d + 3) * 256 + k] = v[3];
}

// attraction: 16 lanes per point (4 points per wave-group), direct global
// atomics. Blocks 0..31 of each batch additionally run repulsion.
// grid (512, B), block 256: 2048 blocks = 8/CU exactly; each wave = 32 points.
__global__ void attraction_repulsion_kernel(
        const float* __restrict__ embed,
        const int* __restrict__ sid,
        const int* __restrict__ first_cp,
        const float* __restrict__ cp_emb,
        const float* __restrict__ cp_embT,
        float* seg_sum, float* rep_sum, int N) {
    int b = blockIdx.y;
    int lane = threadIdx.x & 63;
    int wave = threadIdx.x >> 6;
    int qw = lane >> 4;     // point within 4-point group
    int p  = lane & 15;     // 16B position within a 256B dim-chunk

    const float* embB = embed + (size_t)b * N * 256;
    const float* cpB  = cp_emb + (size_t)b * K_INST * 256;
    const int* sidB   = sid + (size_t)b * N;
    float* segB       = seg_sum + b * K_INST;

    int wid = blockIdx.x * 4 + wave;    // 0..2047
    int i0 = wid * 32;                  // 32 consecutive points per wave

    #pragma unroll 2
    for (int g = 0; g < 8; ++g) {
        int ip = i0 + g * 4 + qw;
        int s = sidB[ip];
        int sc = s < 0 ? 0 : s;
        const float* erow = embB + (size_t)ip * 256 + p * 4;
        const float* crow = cpB + (size_t)sc * 256 + p * 4;
        f32x4 e0 = __builtin_nontemporal_load((const f32x4*)(erow));
        f32x4 e1 = __builtin_nontemporal_load((const f32x4*)(erow + 64));
        f32x4 e2 = __builtin_nontemporal_load((const f32x4*)(erow + 128));
        f32x4 e3 = __builtin_nontemporal_load((const f32x4*)(erow + 192));
        f32x4 c0 = *(const f32x4*)(crow);
        f32x4 c1 = *(const f32x4*)(crow + 64);
        f32x4 c2 = *(const f32x4*)(crow + 128);
        f32x4 c3 = *(const f32x4*)(crow + 192);
        f32x4 d0 = e0 - c0, d1 = e1 - c1, d2 = e2 - c2, d3 = e3 - c3;
        f32x4 acc = d0 * d0 + d1 * d1 + d2 * d2 + d3 * d3;
        float v = acc[0] + acc[1] + acc[2] + acc[3];
        v += __shfl_xor(v, 1);
        v += __shfl_xor(v, 2);
        v += __shfl_xor(v, 4);
        v += __shfl_xor(v, 8);
        if (p == 0 && s >= 0) atomicAdd(&segB[s], v);
    }

    if (blockIdx.x < 32) {
        // ---------------- repulsion (reuses this block) ----------------
        __shared__ float srow[8][264];
        __shared__ float sf[4];
        const int* fcB = first_cp + b * K_INST;
        int i0r = blockIdx.x * 8;
        const float* T = cp_embT + (size_t)b * K_INST * 256;
        {
            int r = threadIdx.x >> 5, cc = (threadIdx.x & 31) * 8;
            f32x4 a = *(const f32x4*)(cpB + (size_t)(i0r + r) * 256 + cc);
            f32x4 bv = *(const f32x4*)(cpB + (size_t)(i0r + r) * 256 + cc + 4);
            srow[r][cc + 0] = a[0]; srow[r][cc + 1] = a[1];
            srow[r][cc + 2] = a[2]; srow[r][cc + 3] = a[3];
            srow[r][cc + 4] = bv[0]; srow[r][cc + 5] = bv[1];
            srow[r][cc + 6] = bv[2]; srow[r][cc + 7] = bv[3];
        }
        __syncthreads();

        int j = threadIdx.x;
        bool has_j = fcB[j] < N;
        float acc[8] = {0.f, 0.f, 0.f, 0.f, 0.f, 0.f, 0.f, 0.f};
        for (int d = 0; d < 256; d += 2) {
            float v0 = T[(size_t)d * 256 + j];
            float v1 = T[(size_t)(d + 1) * 256 + j];
            #pragma unroll
            for (int r = 0; r < 8; ++r) {
                float f0 = srow[r][d] - v0;
                float f1 = srow[r][d + 1] - v1;
                acc[r] += f0 * f0 + f1 * f1;
            }
        }
        float val = 0.f;
        #pragma unroll
        for (int r = 0; r < 8; ++r) {
            bool has_i = fcB[i0r + r] < N;
            if (has_i && has_j) val += expf(-acc[r]);
        }
        val = waveReduceSumF(val);
        if (lane == 0) sf[wave] = val;
        __syncthreads();
        if (threadIdx.x == 0)
            atomicAdd(&rep_sum[b], sf[0] + sf[1] + sf[2] + sf[3]);
    }
}

__global__ void final_kernel(const int* __restrict__ first_cp,
                             const float* __restrict__ seg_sum,
                             const int* __restrict__ seg_cnt,
                             const float* __restrict__ pos_sum,
                             const float* __restrict__ neg_sum,
                             const float* __restrict__ rep_sum,
                             const int* __restrict__ cpv_cnt,
                             const int* __restrict__ noncp_cnt,
                             const int* __restrict__ valid_cnt,
                             float* out, int N, int B) {
    __shared__ float s_att[4];
    __shared__ int s_m[4];
    float loss_sum = 0.f;
    int ok_cnt = 0;
    int wave = threadIdx.x >> 6, lane = threadIdx.x & 63;
    for (int b = 0; b < B; ++b) {
        int k = threadIdx.x;
        int fc = first_cp[b * K_INST + k];
        int has = (fc < N) ? 1 : 0;
        int cnt = seg_cnt[b * K_INST + k];
        float att = (has && cnt > 0) ? (seg_sum[b * K_INST + k] / (float)cnt) : 0.f;
        att = waveReduceSumF(att);
        has = waveReduceSumI(has);
        if (lane == 0) { s_att[wave] = att; s_m[wave] = has; }
        __syncthreads();
        if (threadIdx.x == 0) {
            float attraction = (s_att[0] + s_att[1] + s_att[2] + s_att[3]) * ATTRACTION_W;
            int M = s_m[0] + s_m[1] + s_m[2] + s_m[3];
            float pos = pos_sum[b] / fmaxf((float)cpv_cnt[b], 1.f);
            float neg = neg_sum[b] / fmaxf((float)noncp_cnt[b], 1.f);
            float beta_loss = BETA_POS_W * pos + BETA_NEG_W * neg;
            float rep = 0.f;
            if (M > 1) {
                float mm = (float)M * (float)M;
                rep = (rep_sum[b] / fmaxf(mm, 1.f)) * REPULSION_W;
            }
            float loss = beta_loss + attraction + rep;
            bool ok = (valid_cnt[b] > 0) && (cpv_cnt[b] > 0);
            if (ok) { loss_sum += loss; ok_cnt += 1; }
        }
        __syncthreads();
    }
    if (threadIdx.x == 0) {
        out[0] = (ok_cnt > 0) ? (loss_sum / (float)ok_cnt) : 0.f;
    }
}

extern "C" void kernel_launch(void* const* d_in, const int* in_sizes, int n_in,
                              void* d_out, int out_size, void* d_ws, size_t ws_size,
                              hipStream_t stream) {
    const float* beta  = (const float*)d_in[0];
    const float* embed = (const float*)d_in[1];
    const int* sid     = (const int*)d_in[2];
    const int* is_cp   = (const int*)d_in[3];
    float* out = (float*)d_out;

    const int N = 65536;
    const int B = in_sizes[0] / N;
    (void)n_in; (void)out_size; (void)ws_size;

    char* ws = (char*)d_ws;
    int*   first_cp  = (int*)(ws + 0);          // B*K int
    float* seg_sum   = (float*)(ws + 4096);     // B*K float
    int*   seg_cnt   = (int*)(ws + 8192);       // B*K int
    float* pos_sum   = (float*)(ws + 12288);
    float* neg_sum   = (float*)(ws + 12352);
    float* rep_sum   = (float*)(ws + 12416);
    int*   cpv_cnt   = (int*)(ws + 12480);
    int*   noncp_cnt = (int*)(ws + 12544);
    int*   valid_cnt = (int*)(ws + 12608);
    float* cp_emb    = (float*)(ws + 16384);
    float* cp_embT   = (float*)(ws + 16384 + (size_t)B * K_INST * 256 * 4);

    // first_cp = 0x7F7F7F7F (> N); accumulators = 0
    hipMemsetAsync(first_cp, 0x7F, (size_t)B * K_INST * 4, stream);
    hipMemsetAsync(ws + 4096, 0, 12288, stream);

    stats_kernel<<<dim3(N / 1024, B), dim3(256), 0, stream>>>(
        beta, sid, is_cp, first_cp, pos_sum, neg_sum, seg_cnt,
        cpv_cnt, noncp_cnt, valid_cnt, N);

    gather_kernel<<<dim3(K_INST, B), dim3(64), 0, stream>>>(
        embed, first_cp, cp_emb, cp_embT, N);

    attraction_repulsion_kernel<<<dim3(512, B), dim3(256), 0, stream>>>(
        embed, sid, first_cp, cp_emb, cp_embT, seg_sum, rep_sum, N);

    final_kernel<<<dim3(1), dim3(256), 0, stream>>>(
        first_cp, seg_sum, seg_cnt, pos_sum, neg_sum, rep_sum,
        cpv_cnt, noncp_cnt, valid_cnt, out, N, B);
}